// Round 4
// baseline (1602.235 us; speedup 1.0000x reference)
//
#include <hip/hip_runtime.h>
#include <cstdint>
#include <cstddef>

#define BB 96
#define SS 4
#define TT 16
#define KK 36
#define VDIM 1024
#define QDIM 512
#define HH 512
#define W1R 1536
#define NROWS 3264
#define MM (NROWS * KK)   // 117504

typedef __attribute__((ext_vector_type(8))) short short8;
typedef __attribute__((ext_vector_type(4))) float f32x4;

static __device__ __forceinline__ unsigned short f2bf(float f) {
    union { float f; unsigned u; } v; v.f = f;
    unsigned u = v.u;
    u += 0x7FFFu + ((u >> 16) & 1u);   // RNE
    return (unsigned short)(u >> 16);
}

__device__ __forceinline__ void gload_lds16(const void* g, void* l) {
    __builtin_amdgcn_global_load_lds(
        (const __attribute__((address_space(1))) unsigned int*)g,
        (__attribute__((address_space(3))) unsigned int*)l, 16, 0, 0);
}

// ---------------------------------------------------------------------------
// Kernel 0: transpose slab [kbase, kbase+mask+1) of w1 (fp32 [1536][512])
// into w1T bf16 [512][1536]
// ---------------------------------------------------------------------------
__global__ __launch_bounds__(256) void prep_w1T(const float* __restrict__ w1,
                                                unsigned short* __restrict__ w1T,
                                                int kbase, int mask, int shift) {
    int idx = blockIdx.x * 256 + threadIdx.x;
    int k = idx & mask;
    int c = idx >> shift;
    w1T[(size_t)c * W1R + kbase + k] = f2bf(w1[(size_t)(kbase + k) * HH + c]);
}

// ---------------------------------------------------------------------------
// Kernel 1: per-(b,s) segment starts/lengths via LDS scan (one block)
// ---------------------------------------------------------------------------
__global__ __launch_bounds__(512) void starts_kernel(const int* __restrict__ tags,
                                                     int* __restrict__ starts,
                                                     int* __restrict__ lengths) {
    __shared__ int sl[BB * SS];
    int tid = threadIdx.x;
    int len = 0;
    if (tid < BB * SS) {
#pragma unroll
        for (int i = 0; i < TT; ++i) len += tags[tid * TT + i];
        sl[tid] = len;
    }
    __syncthreads();
    for (int off = 1; off < BB * SS; off <<= 1) {
        int v = 0;
        if (tid < BB * SS && tid >= off) v = sl[tid - off];
        __syncthreads();
        if (tid < BB * SS) sl[tid] += v;
        __syncthreads();
    }
    if (tid < BB * SS) { starts[tid] = sl[tid] - len; lengths[tid] = len; }
}

// ---------------------------------------------------------------------------
// Kernel 2: qproj via MFMA. qp[n][c] = b1[c] + sum_d q[n][d]*w1q[d][c], bf16.
// BM=64, BN=512, K=512 (16 steps of 32). 256 threads = 4 waves (1M x 4N).
// ---------------------------------------------------------------------------
__global__ __launch_bounds__(256, 2) void qproj_mfma(const float* __restrict__ q,
                                                     const unsigned short* __restrict__ w1T,
                                                     const float* __restrict__ b1,
                                                     float* __restrict__ qp) {
    __shared__ __align__(16) unsigned short At[2][64 * 32];    // 8 KB
    __shared__ __align__(16) unsigned short Bt[2][512 * 32];   // 64 KB

    int tid = threadIdx.x, lane = tid & 63, wid = tid >> 6;
    int n0 = blockIdx.x * 64;
    int lr = lane & 15, lg = lane >> 4;

    int arow = tid >> 2, aq = tid & 3;
    const float* a_src = q + (size_t)(n0 + arow) * QDIM + ((aq ^ (arow & 3)) * 8);

    const unsigned short* bsrc[8];
#pragma unroll
    for (int i = 0; i < 8; ++i) {
        int c = wid * 128 + i * 16 + (lane >> 2);
        int g = (lane & 3) ^ ((c ^ (c >> 2)) & 3);
        bsrc[i] = w1T + (size_t)c * W1R + 1024 + g * 8;
    }

    f32x4 acc[4][8];
#pragma unroll
    for (int mt = 0; mt < 4; ++mt)
#pragma unroll
        for (int nt = 0; nt < 8; ++nt) acc[mt][nt] = (f32x4){0.f, 0.f, 0.f, 0.f};

    // prologue
#pragma unroll
    for (int i = 0; i < 8; ++i)
        gload_lds16(bsrc[i], &Bt[0][(wid * 128 + i * 16) * 32]);
    {
        float4 a0 = *(const float4*)a_src;
        float4 a1 = *(const float4*)(a_src + 4);
        unsigned short tc[8] = {f2bf(a0.x), f2bf(a0.y), f2bf(a0.z), f2bf(a0.w),
                                f2bf(a1.x), f2bf(a1.y), f2bf(a1.z), f2bf(a1.w)};
        *(short8*)&At[0][tid * 8] = *(const short8*)tc;
    }
    __syncthreads();

    int buf = 0;
    for (int it = 0; it < 16; ++it) {
        float4 a0n, a1n;
        if (it < 15) {
            int k0 = (it + 1) * 32;
#pragma unroll
            for (int i = 0; i < 8; ++i)
                gload_lds16(bsrc[i] + k0, &Bt[buf ^ 1][(wid * 128 + i * 16) * 32]);
            a0n = *(const float4*)(a_src + k0);
            a1n = *(const float4*)(a_src + k0 + 4);
        }
        short8 af[4], bf[8];
#pragma unroll
        for (int mt = 0; mt < 4; ++mt) {
            int row = mt * 16 + lr;
            af[mt] = *(const short8*)&At[buf][row * 32 + ((lg ^ (row & 3)) * 8)];
        }
#pragma unroll
        for (int nt = 0; nt < 8; ++nt) {
            int col = wid * 128 + nt * 16 + lr;
            bf[nt] = *(const short8*)&Bt[buf][col * 32 + ((lg ^ ((col ^ (col >> 2)) & 3)) * 8)];
        }
        __builtin_amdgcn_s_setprio(1);
#pragma unroll
        for (int mt = 0; mt < 4; ++mt)
#pragma unroll
            for (int nt = 0; nt < 8; ++nt)
                acc[mt][nt] = __builtin_amdgcn_mfma_f32_16x16x32_bf16(af[mt], bf[nt],
                                                                      acc[mt][nt], 0, 0, 0);
        __builtin_amdgcn_s_setprio(0);
        if (it < 15) {
            unsigned short tc[8] = {f2bf(a0n.x), f2bf(a0n.y), f2bf(a0n.z), f2bf(a0n.w),
                                    f2bf(a1n.x), f2bf(a1n.y), f2bf(a1n.z), f2bf(a1n.w)};
            *(short8*)&At[buf ^ 1][tid * 8] = *(const short8*)tc;
        }
        __syncthreads();
        buf ^= 1;
    }

#pragma unroll
    for (int nt = 0; nt < 8; ++nt) {
        int c = wid * 128 + nt * 16 + lr;
        float b1v = b1[c];
#pragma unroll
        for (int mt = 0; mt < 4; ++mt)
#pragma unroll
            for (int r = 0; r < 4; ++r) {
                int row = mt * 16 + lg * 4 + r;
                qp[(size_t)(n0 + row) * HH + c] = acc[mt][nt][r] + b1v;
            }
    }
}

// ---------------------------------------------------------------------------
// Kernel 3: main GEMM. BM=128, BN=512, BK=32. 512 threads = 8 waves (2M x 4N),
// wave tile 64x128. A: coalesced global->reg->bf16->LINEAR ds_write (swizzle
// folded into global source). B: global_load_lds, pre-swizzled source.
// One __syncthreads per K-step, double-buffered. LDS = 80 KB -> 2 blocks/CU.
// Epilogue: relu(acc + qp_lds) . w2 -> logits (b2 cancels in softmax).
// ---------------------------------------------------------------------------
__global__ __launch_bounds__(512, 4) void main_gemm(const float* __restrict__ v,
                                                    const unsigned short* __restrict__ w1T,
                                                    const float* __restrict__ qp,
                                                    const float* __restrict__ w2,
                                                    float* __restrict__ logits) {
    __shared__ __align__(16) unsigned short At[2][128 * 32];   // 16 KB (aliased in epilogue)
    __shared__ __align__(16) unsigned short Bt[2][512 * 32];   // 64 KB

    int tid  = threadIdx.x;
    int lane = tid & 63;
    int wid  = tid >> 6;      // 0..7
    int wm   = wid >> 2;      // 0..1
    int wn   = wid & 3;       // 0..3
    int m0   = blockIdx.x * 128;
    int lr   = lane & 15;
    int lg   = lane >> 4;

    // A staging: thread -> (row = tid>>2, quad = tid&3); global chunk permuted
    int arow = tid >> 2, aq = tid & 3;
    const float* a_src = v + (size_t)(m0 + arow) * VDIM + ((aq ^ (arow & 3)) * 8);

    // B staging: 4 chunks per wave of 16 cols each; pre-swizzled global source
    const unsigned short* bsrc[4];
#pragma unroll
    for (int i = 0; i < 4; ++i) {
        int c = wid * 64 + i * 16 + (lane >> 2);
        int g = (lane & 3) ^ ((c ^ (c >> 2)) & 3);
        bsrc[i] = w1T + (size_t)c * W1R + g * 8;
    }

    f32x4 acc[4][8];
#pragma unroll
    for (int mt = 0; mt < 4; ++mt)
#pragma unroll
        for (int nt = 0; nt < 8; ++nt) acc[mt][nt] = (f32x4){0.f, 0.f, 0.f, 0.f};

    // ---- prologue: stage K-step 0 into buf 0 ----
#pragma unroll
    for (int i = 0; i < 4; ++i)
        gload_lds16(bsrc[i], &Bt[0][(wid * 64 + i * 16) * 32]);
    {
        float4 a0 = *(const float4*)a_src;
        float4 a1 = *(const float4*)(a_src + 4);
        unsigned short tc[8] = {f2bf(a0.x), f2bf(a0.y), f2bf(a0.z), f2bf(a0.w),
                                f2bf(a1.x), f2bf(a1.y), f2bf(a1.z), f2bf(a1.w)};
        *(short8*)&At[0][tid * 8] = *(const short8*)tc;
    }
    __syncthreads();

    int buf = 0;
    for (int it = 0; it < 32; ++it) {
        float4 a0n, a1n;
        if (it < 31) {
            int k0 = (it + 1) * 32;
#pragma unroll
            for (int i = 0; i < 4; ++i)
                gload_lds16(bsrc[i] + k0, &Bt[buf ^ 1][(wid * 64 + i * 16) * 32]);
            a0n = *(const float4*)(a_src + k0);
            a1n = *(const float4*)(a_src + k0 + 4);
        }
        short8 af[4], bf[8];
#pragma unroll
        for (int mt = 0; mt < 4; ++mt) {
            int row = wm * 64 + mt * 16 + lr;
            af[mt] = *(const short8*)&At[buf][row * 32 + ((lg ^ (row & 3)) * 8)];
        }
#pragma unroll
        for (int nt = 0; nt < 8; ++nt) {
            int col = wn * 128 + nt * 16 + lr;
            bf[nt] = *(const short8*)&Bt[buf][col * 32 + ((lg ^ ((col ^ (col >> 2)) & 3)) * 8)];
        }
        __builtin_amdgcn_s_setprio(1);
#pragma unroll
        for (int mt = 0; mt < 4; ++mt)
#pragma unroll
            for (int nt = 0; nt < 8; ++nt)
                acc[mt][nt] = __builtin_amdgcn_mfma_f32_16x16x32_bf16(af[mt], bf[nt],
                                                                      acc[mt][nt], 0, 0, 0);
        __builtin_amdgcn_s_setprio(0);
        if (it < 31) {
            unsigned short tc[8] = {f2bf(a0n.x), f2bf(a0n.y), f2bf(a0n.z), f2bf(a0n.w),
                                    f2bf(a1n.x), f2bf(a1n.y), f2bf(a1n.z), f2bf(a1n.w)};
            *(short8*)&At[buf ^ 1][tid * 8] = *(const short8*)tc;
        }
        __syncthreads();
        buf ^= 1;
    }

    // ---- epilogue: preload qp slab (<=5 n-rows) into LDS (alias At) ----
    float* qs = (float*)&At[0][0];          // 5*512 floats = 10 KB
    float* fl = qs + 5 * HH;                // 8*64 floats = 2 KB (total 12 KB <= 16 KB)
    int n0 = m0 / KK;
    for (int i = tid; i < 5 * HH; i += 512) {
        int nn = n0 + (i >> 9);
        if (nn >= NROWS) nn = NROWS - 1;
        qs[i] = qp[(size_t)nn * HH + (i & (HH - 1))];
    }
    __syncthreads();

    int nidx[4][4];
#pragma unroll
    for (int mt = 0; mt < 4; ++mt)
#pragma unroll
        for (int r = 0; r < 4; ++r)
            nidx[mt][r] = (m0 + wm * 64 + mt * 16 + lg * 4 + r) / KK - n0;

    float part[4][4] = {{0.f}};
#pragma unroll
    for (int nt = 0; nt < 8; ++nt) {
        int c = wn * 128 + nt * 16 + lr;
        float w2v = w2[c];
#pragma unroll
        for (int mt = 0; mt < 4; ++mt)
#pragma unroll
            for (int r = 0; r < 4; ++r) {
                float pre = acc[mt][nt][r] + qs[nidx[mt][r] * HH + c];
                part[mt][r] += fmaxf(pre, 0.f) * w2v;
            }
    }
#pragma unroll
    for (int mt = 0; mt < 4; ++mt)
#pragma unroll
        for (int r = 0; r < 4; ++r) {
            float s = part[mt][r];
            s += __shfl_xor(s, 1, 64);
            s += __shfl_xor(s, 2, 64);
            s += __shfl_xor(s, 4, 64);
            s += __shfl_xor(s, 8, 64);
            if (lr == 0) fl[(wm * 4 + wn) * 64 + mt * 16 + lg * 4 + r] = s;
        }
    __syncthreads();
    if (tid < 128) {
        int wmx = tid >> 6, r = tid & 63;
        float s = fl[(wmx * 4 + 0) * 64 + r] + fl[(wmx * 4 + 1) * 64 + r]
                + fl[(wmx * 4 + 2) * 64 + r] + fl[(wmx * 4 + 3) * 64 + r];
        logits[m0 + wmx * 64 + r] = s;
    }
}

// ---------------------------------------------------------------------------
// Kernel 4: masked softmax. One wave per (b,s,t).
// ---------------------------------------------------------------------------
__global__ __launch_bounds__(256) void softmax_kernel(const float* __restrict__ logits,
                                                      const float* __restrict__ box_mask,
                                                      const int* __restrict__ starts,
                                                      const int* __restrict__ lengths,
                                                      float* __restrict__ out) {
    int lane = threadIdx.x & 63;
    int g = blockIdx.x * 4 + (threadIdx.x >> 6);   // 0 .. B*S*T-1
    int t   = g & (TT - 1);
    int row = g >> 4;
    int b   = row >> 2;

    int length = lengths[row];
    int start  = starts[row];

    int k = lane;
    bool kv = k < KK;
    float mval = kv ? box_mask[b * KK + k] : 0.f;
    bool act = kv && (mval != 0.f);

    float l = 0.f;
    if (act && t < length) l = logits[(size_t)(start + t) * KK + k];

    float lm = act ? l : -1e30f;
#pragma unroll
    for (int off = 32; off >= 1; off >>= 1) lm = fmaxf(lm, __shfl_xor(lm, off, 64));

    float e = act ? expf(l - lm) : 0.f;
    float se = e;
#pragma unroll
    for (int off = 32; off >= 1; off >>= 1) se += __shfl_xor(se, off, 64);

    if (kv) out[(size_t)g * KK + k] = e / se;
}

// ---------------------------------------------------------------------------
extern "C" void kernel_launch(void* const* d_in, const int* in_sizes, int n_in,
                              void* d_out, int out_size, void* d_ws, size_t ws_size,
                              hipStream_t stream) {
    const float* v        = (const float*)d_in[0];
    const float* q        = (const float*)d_in[1];
    const float* box_mask = (const float*)d_in[2];
    const int*   tags     = (const int*)d_in[3];
    const float* w1       = (const float*)d_in[4];
    const float* b1       = (const float*)d_in[5];
    const float* w2       = (const float*)d_in[6];

    unsigned short* w1T   = (unsigned short*)d_ws;                       // 1.5 MB
    float* qp      = (float*)((char*)d_ws + 1572864);                    // 6.68 MB
    float* logits  = (float*)((char*)d_ws + 1572864 + 6684672);          // 470 KB
    int*   starts  = (int*)((char*)d_ws + 1572864 + 6684672 + 470016);
    int*   lengths = (int*)((char*)d_ws + 1572864 + 6684672 + 470016 + 1536);
    float* out     = (float*)d_out;

    hipLaunchKernelGGL(prep_w1T, dim3(2048), dim3(256), 0, stream, w1, w1T, 0, 1023, 10);
    hipLaunchKernelGGL(prep_w1T, dim3(1024), dim3(256), 0, stream, w1, w1T, 1024, 511, 9);
    hipLaunchKernelGGL(starts_kernel, dim3(1), dim3(512), 0, stream, tags, starts, lengths);
    hipLaunchKernelGGL(qproj_mfma, dim3(NROWS / 64), dim3(256), 0, stream, q, w1T, b1, qp);
    hipLaunchKernelGGL(main_gemm, dim3(MM / 128), dim3(512), 0, stream,
                       v, w1T, qp, w2, logits);
    hipLaunchKernelGGL(softmax_kernel, dim3((BB * SS * TT) / 4), dim3(256), 0, stream,
                       logits, box_mask, starts, lengths, out);
}

// Round 5
// 328.452 us; speedup vs baseline: 4.8781x; 4.8781x over previous
//
#include <hip/hip_runtime.h>
#include <cstdint>
#include <cstddef>

#define BB 96
#define SS 4
#define TT 16
#define KK 36
#define VDIM 1024
#define QDIM 512
#define HH 512
#define W1R 1536
#define NROWS 3264
#define MM (NROWS * KK)   // 117504

typedef __attribute__((ext_vector_type(8))) short short8;
typedef __attribute__((ext_vector_type(4))) float f32x4;
typedef __attribute__((ext_vector_type(4))) unsigned short ushort4v;

static __device__ __forceinline__ unsigned short f2bf(float f) {
    union { float f; unsigned u; } v; v.f = f;
    unsigned u = v.u;
    u += 0x7FFFu + ((u >> 16) & 1u);   // RNE
    return (unsigned short)(u >> 16);
}

__device__ __forceinline__ void gload_lds16(const void* g, void* l) {
    __builtin_amdgcn_global_load_lds(
        (const __attribute__((address_space(1))) unsigned int*)g,
        (__attribute__((address_space(3))) unsigned int*)l, 16, 0, 0);
}

#define SB() __builtin_amdgcn_sched_barrier(0)

// ---------------------------------------------------------------------------
// Kernel 0: w1 (fp32 [1536][512]) -> w1T bf16 [512][1536]. grid (6, 512).
// ---------------------------------------------------------------------------
__global__ __launch_bounds__(256) void prep_w1T(const float* __restrict__ w1,
                                                unsigned short* __restrict__ w1T) {
    int k = blockIdx.x * 256 + threadIdx.x;   // 0..1535
    int c = blockIdx.y;                       // 0..511
    w1T[(size_t)c * W1R + k] = f2bf(w1[(size_t)k * HH + c]);
}

// ---------------------------------------------------------------------------
// Kernel 1: per-(b,s) segment starts/lengths via LDS scan (one block)
// ---------------------------------------------------------------------------
__global__ __launch_bounds__(512) void starts_kernel(const int* __restrict__ tags,
                                                     int* __restrict__ starts,
                                                     int* __restrict__ lengths) {
    __shared__ int sl[BB * SS];
    int tid = threadIdx.x;
    int len = 0;
    if (tid < BB * SS) {
#pragma unroll
        for (int i = 0; i < TT; ++i) len += tags[tid * TT + i];
        sl[tid] = len;
    }
    __syncthreads();
    for (int off = 1; off < BB * SS; off <<= 1) {
        int v = 0;
        if (tid < BB * SS && tid >= off) v = sl[tid - off];
        __syncthreads();
        if (tid < BB * SS) sl[tid] += v;
        __syncthreads();
    }
    if (tid < BB * SS) { starts[tid] = sl[tid] - len; lengths[tid] = len; }
}

// ---------------------------------------------------------------------------
// Kernel 2: qproj via MFMA. Tile 64(M) x 128(N), K=512 (8 steps of 64).
// grid 51*4. 256 thr = 4 waves (2x2), wave tile 32x64, acc[2][4].
// Same swizzled-LDS pipeline as main_gemm.
// ---------------------------------------------------------------------------
__global__ __launch_bounds__(256, 3) void qproj_mfma(const float* __restrict__ q,
                                                     const unsigned short* __restrict__ w1T,
                                                     const float* __restrict__ b1,
                                                     float* __restrict__ qp) {
    __shared__ __align__(16) unsigned short At[2][64 * 64];    // 16 KB
    __shared__ __align__(16) unsigned short Bt[2][128 * 64];   // 32 KB

    int tid = threadIdx.x, lane = tid & 63, wid = tid >> 6;
    int wm = wid >> 1, wn = wid & 1;
    int bx = blockIdx.x;
    int nb = bx & 3, mb = bx >> 2;
    int n0q = mb * 64, cb = nb * 128;
    int lr = lane & 15, lg = lane >> 4;

    const float* a_base = q + (size_t)(n0q + wid * 16 + (lane >> 4)) * QDIM + (lane & 15) * 4;
    const unsigned short* b_base = w1T + (size_t)(cb + wid * 32 + (lane >> 3)) * W1R + 1024
                                 + (((lane & 7) ^ (lane >> 3)) * 8);

    f32x4 acc[2][4];
#pragma unroll
    for (int mt = 0; mt < 2; ++mt)
#pragma unroll
        for (int nt = 0; nt < 4; ++nt) acc[mt][nt] = (f32x4){0.f, 0.f, 0.f, 0.f};

#define QP_CVT_WRITE(DST, AR)                                                  \
    _Pragma("unroll") for (int p = 0; p < 4; ++p) {                            \
        int r = wid * 16 + (lane >> 4) + p * 4;                                \
        int boff = r * 128 + ((((lane & 15) * 8)) ^ ((r & 7) << 4));           \
        unsigned short t4[4] = {f2bf(AR[p].x), f2bf(AR[p].y),                  \
                                f2bf(AR[p].z), f2bf(AR[p].w)};                 \
        *(ushort4v*)((char*)(DST) + boff) = *(const ushort4v*)t4;              \
    }

#define QP_COMPUTE(AC, BC)                                                     \
    _Pragma("unroll") for (int kk = 0; kk < 2; ++kk) {                         \
        short8 af[2], bf[4];                                                   \
        _Pragma("unroll") for (int mt = 0; mt < 2; ++mt) {                     \
            int R = wm * 32 + mt * 16 + lr;                                    \
            int off = R * 128 + ((kk * 64 + lg * 16) ^ ((R & 7) << 4));        \
            af[mt] = *(const short8*)((const char*)(AC) + off);                \
        }                                                                      \
        _Pragma("unroll") for (int nt = 0; nt < 4; ++nt) {                     \
            int R = wn * 64 + nt * 16 + lr;                                    \
            int off = R * 128 + ((kk * 64 + lg * 16) ^ ((R & 7) << 4));        \
            bf[nt] = *(const short8*)((const char*)(BC) + off);                \
        }                                                                      \
        __builtin_amdgcn_s_setprio(1);                                         \
        _Pragma("unroll") for (int mt = 0; mt < 2; ++mt)                       \
            _Pragma("unroll") for (int nt = 0; nt < 4; ++nt)                   \
                acc[mt][nt] = __builtin_amdgcn_mfma_f32_16x16x32_bf16(         \
                    af[mt], bf[nt], acc[mt][nt], 0, 0, 0);                     \
        __builtin_amdgcn_s_setprio(0);                                         \
    }

    // prologue
    {
        float4 ar[4];
#pragma unroll
        for (int p = 0; p < 4; ++p) ar[p] = *(const float4*)(a_base + (size_t)p * 4 * QDIM);
#pragma unroll
        for (int o = 0; o < 4; ++o)
            gload_lds16(b_base + (size_t)o * 8 * W1R, &Bt[0][(wid * 32 + o * 8) * 64]);
        SB();
        QP_CVT_WRITE(&At[0][0], ar)
    }
    for (int t = 0; t < 7; ++t) {
        int k0 = (t + 1) * 64;
        const unsigned short* Ac = &At[t & 1][0];
        const unsigned short* Bc = &Bt[t & 1][0];
        unsigned short* An = &At[(t + 1) & 1][0];
        unsigned short* Bn = &Bt[(t + 1) & 1][0];
        float4 ar[4];
#pragma unroll
        for (int p = 0; p < 4; ++p)
            ar[p] = *(const float4*)(a_base + (size_t)p * 4 * QDIM + k0);
#pragma unroll
        for (int o = 0; o < 4; ++o)
            gload_lds16(b_base + (size_t)o * 8 * W1R + k0, &Bn[(wid * 32 + o * 8) * 64]);
        SB();
        asm volatile("s_waitcnt vmcnt(8)" ::: "memory");
        asm volatile("s_waitcnt lgkmcnt(0)" ::: "memory");
        __builtin_amdgcn_s_barrier();
        SB();
        QP_COMPUTE(Ac, Bc)
        SB();
        QP_CVT_WRITE(An, ar)
    }
    SB();
    asm volatile("s_waitcnt vmcnt(0)" ::: "memory");
    asm volatile("s_waitcnt lgkmcnt(0)" ::: "memory");
    __builtin_amdgcn_s_barrier();
    SB();
    QP_COMPUTE(&At[1][0], &Bt[1][0])
#undef QP_COMPUTE
#undef QP_CVT_WRITE

    // store qp + b1
#pragma unroll
    for (int nt = 0; nt < 4; ++nt) {
        int c = cb + wn * 64 + nt * 16 + lr;
        float b1v = b1[c];
#pragma unroll
        for (int mt = 0; mt < 2; ++mt)
#pragma unroll
            for (int r = 0; r < 4; ++r) {
                int row = wm * 32 + mt * 16 + lg * 4 + r;
                qp[(size_t)(n0q + row) * HH + c] = acc[mt][nt][r] + b1v;
            }
    }
}

// ---------------------------------------------------------------------------
// Kernel 3: main GEMM. Tile 128(M) x 128(N), BK=64, 16 K-steps. grid 918*4.
// 256 thr = 4 waves (2x2), wave tile 64x64, acc[4][4].
// A: coalesced global->reg->bf16->swizzled ds_write_b64 (double-buffered).
// B: global_load_lds (linear dest, pre-swizzled per-lane source).
// One raw s_barrier per K-step, counted vmcnt(12) (never 0 in loop).
// Epilogue: relu(acc + qp) . w2 -> partial logits for this n-block.
// ---------------------------------------------------------------------------
__global__ __launch_bounds__(256, 2) void main_gemm(const float* __restrict__ v,
                                                    const unsigned short* __restrict__ w1T,
                                                    const float* __restrict__ qp,
                                                    const float* __restrict__ w2,
                                                    float* __restrict__ logits4) {
    __shared__ __align__(16) unsigned short At[2][128 * 64];   // 32 KB
    __shared__ __align__(16) unsigned short Bt[2][128 * 64];   // 32 KB

    int tid = threadIdx.x, lane = tid & 63, wid = tid >> 6;
    int wm = wid >> 1, wn = wid & 1;
    int bx = blockIdx.x;
    int nb = bx & 3, mb = bx >> 2;
    int m0 = mb * 128, cb = nb * 128;
    int lr = lane & 15, lg = lane >> 4;

    // A: pass p loads row (wid*32 + (lane>>4) + p*4), 16B at float-col (lane&15)*4
    const float* a_base = v + (size_t)(m0 + wid * 32 + (lane >> 4)) * VDIM + (lane & 15) * 4;
    // B: op o stages rows [wid*32+o*8, +8); lane i -> row +(i>>3), k-chunk (i&7)^(i>>3)
    const unsigned short* b_base = w1T + (size_t)(cb + wid * 32 + (lane >> 3)) * W1R
                                 + (((lane & 7) ^ (lane >> 3)) * 8);

    f32x4 acc[4][4];
#pragma unroll
    for (int mt = 0; mt < 4; ++mt)
#pragma unroll
        for (int nt = 0; nt < 4; ++nt) acc[mt][nt] = (f32x4){0.f, 0.f, 0.f, 0.f};

#define MG_CVT_WRITE(DST, AR)                                                  \
    _Pragma("unroll") for (int p = 0; p < 8; ++p) {                            \
        int r = wid * 32 + (lane >> 4) + p * 4;                                \
        int boff = r * 128 + ((((lane & 15) * 8)) ^ ((r & 7) << 4));           \
        unsigned short t4[4] = {f2bf(AR[p].x), f2bf(AR[p].y),                  \
                                f2bf(AR[p].z), f2bf(AR[p].w)};                 \
        *(ushort4v*)((char*)(DST) + boff) = *(const ushort4v*)t4;              \
    }

#define MG_COMPUTE(AC, BC)                                                     \
    _Pragma("unroll") for (int kk = 0; kk < 2; ++kk) {                         \
        short8 af[4], bf[4];                                                   \
        _Pragma("unroll") for (int mt = 0; mt < 4; ++mt) {                     \
            int R = wm * 64 + mt * 16 + lr;                                    \
            int off = R * 128 + ((kk * 64 + lg * 16) ^ ((R & 7) << 4));        \
            af[mt] = *(const short8*)((const char*)(AC) + off);                \
        }                                                                      \
        _Pragma("unroll") for (int nt = 0; nt < 4; ++nt) {                     \
            int R = wn * 64 + nt * 16 + lr;                                    \
            int off = R * 128 + ((kk * 64 + lg * 16) ^ ((R & 7) << 4));        \
            bf[nt] = *(const short8*)((const char*)(BC) + off);                \
        }                                                                      \
        __builtin_amdgcn_s_setprio(1);                                         \
        _Pragma("unroll") for (int mt = 0; mt < 4; ++mt)                       \
            _Pragma("unroll") for (int nt = 0; nt < 4; ++nt)                   \
                acc[mt][nt] = __builtin_amdgcn_mfma_f32_16x16x32_bf16(         \
                    af[mt], bf[nt], acc[mt][nt], 0, 0, 0);                     \
        __builtin_amdgcn_s_setprio(0);                                         \
    }

    // ---- prologue: A(0) loads, B(0) gload_lds, cvt->At[0] ----
    {
        float4 ar[8];
#pragma unroll
        for (int p = 0; p < 8; ++p) ar[p] = *(const float4*)(a_base + (size_t)p * 4 * VDIM);
#pragma unroll
        for (int o = 0; o < 4; ++o)
            gload_lds16(b_base + (size_t)o * 8 * W1R, &Bt[0][(wid * 32 + o * 8) * 64]);
        SB();
        MG_CVT_WRITE(&At[0][0], ar)
    }

    for (int t = 0; t < 15; ++t) {
        int k0 = (t + 1) * 64;
        const unsigned short* Ac = &At[t & 1][0];
        const unsigned short* Bc = &Bt[t & 1][0];
        unsigned short* An = &At[(t + 1) & 1][0];
        unsigned short* Bn = &Bt[(t + 1) & 1][0];
        // (a) A(t+1) -> regs, (b) B(t+1) -> LDS DMA   [12 VMEM ops]
        float4 ar[8];
#pragma unroll
        for (int p = 0; p < 8; ++p)
            ar[p] = *(const float4*)(a_base + (size_t)p * 4 * VDIM + k0);
#pragma unroll
        for (int o = 0; o < 4; ++o)
            gload_lds16(b_base + (size_t)o * 8 * W1R + k0, &Bn[(wid * 32 + o * 8) * 64]);
        SB();
        // (c) B(t) staged (everything older than the 12 above)
        asm volatile("s_waitcnt vmcnt(12)" ::: "memory");
        asm volatile("s_waitcnt lgkmcnt(0)" ::: "memory");
        __builtin_amdgcn_s_barrier();
        SB();
        // (e) compute current buffers
        MG_COMPUTE(Ac, Bc)
        SB();
        // (f) cvt A(t+1) (compiler waits its own regs) -> swizzled write
        MG_CVT_WRITE(An, ar)
    }
    SB();
    asm volatile("s_waitcnt vmcnt(0)" ::: "memory");
    asm volatile("s_waitcnt lgkmcnt(0)" ::: "memory");
    __builtin_amdgcn_s_barrier();
    SB();
    MG_COMPUTE(&At[1][0], &Bt[1][0])
#undef MG_COMPUTE
#undef MG_CVT_WRITE

    // ---- epilogue: relu(acc + qp) . w2 -> partial logits for cols [cb,cb+128)
    __syncthreads();
    float* qs = (float*)&At[0][0];      // 5 x 128 slab of qp
    float* fl = qs + 5 * 128;           // 2 x 128 reduction scratch
    int n0 = m0 / KK;
    for (int i = tid; i < 5 * 128; i += 256) {
        int nn = n0 + (i >> 7);
        if (nn >= NROWS) nn = NROWS - 1;
        qs[i] = qp[(size_t)nn * HH + cb + (i & 127)];
    }
    __syncthreads();

    float part[4][4] = {{0.f}};
#pragma unroll
    for (int nt = 0; nt < 4; ++nt) {
        int c = wn * 64 + nt * 16 + lr;
        float w2v = w2[cb + c];
#pragma unroll
        for (int mt = 0; mt < 4; ++mt)
#pragma unroll
            for (int r = 0; r < 4; ++r) {
                int row = wm * 64 + mt * 16 + lg * 4 + r;
                int ni = (m0 + row) / KK - n0;
                float pre = acc[mt][nt][r] + qs[ni * 128 + c];
                part[mt][r] += fmaxf(pre, 0.f) * w2v;
            }
    }
#pragma unroll
    for (int mt = 0; mt < 4; ++mt)
#pragma unroll
        for (int r = 0; r < 4; ++r) {
            float s = part[mt][r];
            s += __shfl_xor(s, 1, 64);
            s += __shfl_xor(s, 2, 64);
            s += __shfl_xor(s, 4, 64);
            s += __shfl_xor(s, 8, 64);
            if (lr == 0) fl[wn * 128 + wm * 64 + mt * 16 + lg * 4 + r] = s;
        }
    __syncthreads();
    if (tid < 128)
        logits4[(size_t)nb * MM + m0 + tid] = fl[tid] + fl[128 + tid];
}

// ---------------------------------------------------------------------------
// Kernel 4: masked softmax. One wave per (b,s,t); sums 4 logit partials.
// ---------------------------------------------------------------------------
__global__ __launch_bounds__(256) void softmax_kernel(const float* __restrict__ logits4,
                                                      const float* __restrict__ box_mask,
                                                      const int* __restrict__ starts,
                                                      const int* __restrict__ lengths,
                                                      float* __restrict__ out) {
    int lane = threadIdx.x & 63;
    int g = blockIdx.x * 4 + (threadIdx.x >> 6);   // 0 .. B*S*T-1
    int t   = g & (TT - 1);
    int row = g >> 4;
    int b   = row >> 2;

    int length = lengths[row];
    int start  = starts[row];

    int k = lane;
    bool kv = k < KK;
    float mval = kv ? box_mask[b * KK + k] : 0.f;
    bool act = kv && (mval != 0.f);

    float l = 0.f;
    if (act && t < length) {
        size_t idx = (size_t)(start + t) * KK + k;
        l = logits4[idx] + logits4[MM + idx] + logits4[2 * (size_t)MM + idx]
          + logits4[3 * (size_t)MM + idx];
    }

    float lm = act ? l : -1e30f;
#pragma unroll
    for (int off = 32; off >= 1; off >>= 1) lm = fmaxf(lm, __shfl_xor(lm, off, 64));

    float e = act ? expf(l - lm) : 0.f;
    float se = e;
#pragma unroll
    for (int off = 32; off >= 1; off >>= 1) se += __shfl_xor(se, off, 64);

    if (kv) out[(size_t)g * KK + k] = e / se;
}

// ---------------------------------------------------------------------------
extern "C" void kernel_launch(void* const* d_in, const int* in_sizes, int n_in,
                              void* d_out, int out_size, void* d_ws, size_t ws_size,
                              hipStream_t stream) {
    const float* v        = (const float*)d_in[0];
    const float* q        = (const float*)d_in[1];
    const float* box_mask = (const float*)d_in[2];
    const int*   tags     = (const int*)d_in[3];
    const float* w1       = (const float*)d_in[4];
    const float* b1       = (const float*)d_in[5];
    const float* w2       = (const float*)d_in[6];

    char* ws = (char*)d_ws;
    unsigned short* w1T   = (unsigned short*)ws;                 // 1,572,864 B
    float* qp      = (float*)(ws + 1572864);                     // 6,684,672 B
    float* logits4 = (float*)(ws + 1572864 + 6684672);           // 1,880,064 B
    int*   starts  = (int*)(ws + 1572864 + 6684672 + 1880064);
    int*   lengths = (int*)(ws + 1572864 + 6684672 + 1880064 + 1536);
    float* out     = (float*)d_out;

    hipLaunchKernelGGL(prep_w1T, dim3(6, 512), dim3(256), 0, stream, w1, w1T);
    hipLaunchKernelGGL(starts_kernel, dim3(1), dim3(512), 0, stream, tags, starts, lengths);
    hipLaunchKernelGGL(qproj_mfma, dim3((NROWS / 64) * 4), dim3(256), 0, stream,
                       q, w1T, b1, qp);
    hipLaunchKernelGGL(main_gemm, dim3((MM / 128) * 4), dim3(256), 0, stream,
                       v, w1T, qp, w2, logits4);
    hipLaunchKernelGGL(softmax_kernel, dim3((BB * SS * TT) / 4), dim3(256), 0, stream,
                       logits4, box_mask, starts, lengths, out);
}

// Round 6
// 237.346 us; speedup vs baseline: 6.7506x; 1.3839x over previous
//
#include <hip/hip_runtime.h>
#include <cstdint>
#include <cstddef>

#define BB 96
#define SS 4
#define TT 16
#define KK 36
#define VDIM 1024
#define QDIM 512
#define HH 512
#define W1R 1536
#define NROWS 3264
#define MM (NROWS * KK)   // 117504

typedef __attribute__((ext_vector_type(8))) short short8;
typedef __attribute__((ext_vector_type(4))) float f32x4;
typedef __attribute__((ext_vector_type(4))) unsigned short ushort4v;

static __device__ __forceinline__ unsigned short f2bf(float f) {
    union { float f; unsigned u; } v; v.f = f;
    unsigned u = v.u;
    u += 0x7FFFu + ((u >> 16) & 1u);   // RNE
    return (unsigned short)(u >> 16);
}

__device__ __forceinline__ void gload_lds16(const void* g, void* l) {
    __builtin_amdgcn_global_load_lds(
        (const __attribute__((address_space(1))) unsigned int*)g,
        (__attribute__((address_space(3))) unsigned int*)l, 16, 0, 0);
}

#define SB() __builtin_amdgcn_sched_barrier(0)

// ---------------------------------------------------------------------------
// Kernel 0: w1 (fp32 [1536][512]) -> w1T bf16 [512][1536]. grid (6, 512).
// ---------------------------------------------------------------------------
__global__ __launch_bounds__(256) void prep_w1T(const float* __restrict__ w1,
                                                unsigned short* __restrict__ w1T) {
    int k = blockIdx.x * 256 + threadIdx.x;   // 0..1535
    int c = blockIdx.y;                       // 0..511
    w1T[(size_t)c * W1R + k] = f2bf(w1[(size_t)k * HH + c]);
}

// ---------------------------------------------------------------------------
// Kernel 1: per-(b,s) segment starts/lengths via LDS scan (one block)
// ---------------------------------------------------------------------------
__global__ __launch_bounds__(512) void starts_kernel(const int* __restrict__ tags,
                                                     int* __restrict__ starts,
                                                     int* __restrict__ lengths) {
    __shared__ int sl[BB * SS];
    int tid = threadIdx.x;
    int len = 0;
    if (tid < BB * SS) {
#pragma unroll
        for (int i = 0; i < TT; ++i) len += tags[tid * TT + i];
        sl[tid] = len;
    }
    __syncthreads();
    for (int off = 1; off < BB * SS; off <<= 1) {
        int v = 0;
        if (tid < BB * SS && tid >= off) v = sl[tid - off];
        __syncthreads();
        if (tid < BB * SS) sl[tid] += v;
        __syncthreads();
    }
    if (tid < BB * SS) { starts[tid] = sl[tid] - len; lengths[tid] = len; }
}

// ---------------------------------------------------------------------------
// Kernel 2: qproj via MFMA. Tile 64(M) x 128(N), K=512 (8 steps of 64).
// grid 51*4. 256 thr = 4 waves (2x2), wave tile 32x64, acc[2][4].
// ---------------------------------------------------------------------------
__global__ __launch_bounds__(256, 3) void qproj_mfma(const float* __restrict__ q,
                                                     const unsigned short* __restrict__ w1T,
                                                     const float* __restrict__ b1,
                                                     float* __restrict__ qp) {
    __shared__ __align__(16) unsigned short At[2][64 * 64];    // 16 KB
    __shared__ __align__(16) unsigned short Bt[2][128 * 64];   // 32 KB

    int tid = threadIdx.x, lane = tid & 63, wid = tid >> 6;
    int wm = wid >> 1, wn = wid & 1;
    int bx = blockIdx.x;
    int nb = bx & 3, mb = bx >> 2;
    int n0q = mb * 64, cb = nb * 128;
    int lr = lane & 15, lg = lane >> 4;

    const float* a_base = q + (size_t)(n0q + wid * 16 + (lane >> 4)) * QDIM + (lane & 15) * 4;
    const unsigned short* b_base = w1T + (size_t)(cb + wid * 32 + (lane >> 3)) * W1R + 1024
                                 + (((lane & 7) ^ (lane >> 3)) * 8);

    f32x4 acc[2][4];
#pragma unroll
    for (int mt = 0; mt < 2; ++mt)
#pragma unroll
        for (int nt = 0; nt < 4; ++nt) acc[mt][nt] = (f32x4){0.f, 0.f, 0.f, 0.f};

#define QP_CVT_WRITE(DST, AR)                                                  \
    _Pragma("unroll") for (int p = 0; p < 4; ++p) {                            \
        int r = wid * 16 + (lane >> 4) + p * 4;                                \
        int boff = r * 128 + ((((lane & 15) * 8)) ^ ((r & 7) << 4));           \
        unsigned short t4[4] = {f2bf(AR[p].x), f2bf(AR[p].y),                  \
                                f2bf(AR[p].z), f2bf(AR[p].w)};                 \
        *(ushort4v*)((char*)(DST) + boff) = *(const ushort4v*)t4;              \
    }

#define QP_COMPUTE(AC, BC)                                                     \
    _Pragma("unroll") for (int kk = 0; kk < 2; ++kk) {                         \
        short8 af[2], bf[4];                                                   \
        _Pragma("unroll") for (int mt = 0; mt < 2; ++mt) {                     \
            int R = wm * 32 + mt * 16 + lr;                                    \
            int off = R * 128 + ((kk * 64 + lg * 16) ^ ((R & 7) << 4));        \
            af[mt] = *(const short8*)((const char*)(AC) + off);                \
        }                                                                      \
        _Pragma("unroll") for (int nt = 0; nt < 4; ++nt) {                     \
            int R = wn * 64 + nt * 16 + lr;                                    \
            int off = R * 128 + ((kk * 64 + lg * 16) ^ ((R & 7) << 4));        \
            bf[nt] = *(const short8*)((const char*)(BC) + off);                \
        }                                                                      \
        __builtin_amdgcn_s_setprio(1);                                         \
        _Pragma("unroll") for (int mt = 0; mt < 2; ++mt)                       \
            _Pragma("unroll") for (int nt = 0; nt < 4; ++nt)                   \
                acc[mt][nt] = __builtin_amdgcn_mfma_f32_16x16x32_bf16(         \
                    af[mt], bf[nt], acc[mt][nt], 0, 0, 0);                     \
        __builtin_amdgcn_s_setprio(0);                                         \
    }

    // prologue
    {
        float4 ar[4];
#pragma unroll
        for (int p = 0; p < 4; ++p) ar[p] = *(const float4*)(a_base + (size_t)p * 4 * QDIM);
#pragma unroll
        for (int o = 0; o < 4; ++o)
            gload_lds16(b_base + (size_t)o * 8 * W1R, &Bt[0][(wid * 32 + o * 8) * 64]);
        SB();
        QP_CVT_WRITE(&At[0][0], ar)
    }
#pragma unroll 1
    for (int t = 0; t < 7; ++t) {
        int k0 = (t + 1) * 64;
        const unsigned short* Ac = &At[t & 1][0];
        const unsigned short* Bc = &Bt[t & 1][0];
        unsigned short* An = &At[(t + 1) & 1][0];
        unsigned short* Bn = &Bt[(t + 1) & 1][0];
        float4 ar[4];
#pragma unroll
        for (int p = 0; p < 4; ++p)
            ar[p] = *(const float4*)(a_base + (size_t)p * 4 * QDIM + k0);
#pragma unroll
        for (int o = 0; o < 4; ++o)
            gload_lds16(b_base + (size_t)o * 8 * W1R + k0, &Bn[(wid * 32 + o * 8) * 64]);
        SB();
        asm volatile("s_waitcnt vmcnt(8)" ::: "memory");
        asm volatile("s_waitcnt lgkmcnt(0)" ::: "memory");
        __builtin_amdgcn_s_barrier();
        SB();
        QP_COMPUTE(Ac, Bc)
        SB();
        QP_CVT_WRITE(An, ar)
    }
    SB();
    asm volatile("s_waitcnt vmcnt(0)" ::: "memory");
    asm volatile("s_waitcnt lgkmcnt(0)" ::: "memory");
    __builtin_amdgcn_s_barrier();
    SB();
    QP_COMPUTE(&At[1][0], &Bt[1][0])
#undef QP_COMPUTE
#undef QP_CVT_WRITE

    // store qp + b1
#pragma unroll
    for (int nt = 0; nt < 4; ++nt) {
        int c = cb + wn * 64 + nt * 16 + lr;
        float b1v = b1[c];
#pragma unroll
        for (int mt = 0; mt < 2; ++mt)
#pragma unroll
            for (int r = 0; r < 4; ++r) {
                int row = wm * 32 + mt * 16 + lg * 4 + r;
                qp[(size_t)(n0q + row) * HH + c] = acc[mt][nt][r] + b1v;
            }
    }
}

// ---------------------------------------------------------------------------
// Kernel 3: main GEMM. Tile 128(M) x 128(N), BK=64, 16 K-steps.
// grid 3672 = 8 XCD-chunks of 459; orig id = (bx&7)*459 + (bx>>3) so each
// XCD owns a contiguous mb range (all 4 nb of a panel on one XCD -> v panel
// fetched once per XCD).
// 256 thr = 4 waves (2x2), wave tile 64x64, acc[4][4].
// A: SINGLE-buffered LDS (af pre-read to regs + 2nd barrier before overwrite).
// B: double-buffered global_load_lds, counted vmcnt(12) (never 0 in loop).
// LDS = 48 KB -> 3 blocks/CU.
// ---------------------------------------------------------------------------
__global__ __launch_bounds__(256, 3) void main_gemm(const float* __restrict__ v,
                                                    const unsigned short* __restrict__ w1T,
                                                    const float* __restrict__ qp,
                                                    const float* __restrict__ w2,
                                                    float* __restrict__ logits4) {
    __shared__ __align__(16) unsigned short At[128 * 64];      // 16 KB (single buf)
    __shared__ __align__(16) unsigned short Bt[2][128 * 64];   // 32 KB

    int tid = threadIdx.x, lane = tid & 63, wid = tid >> 6;
    int wm = wid >> 1, wn = wid & 1;
    int bx = blockIdx.x;
    int orig = (bx & 7) * 459 + (bx >> 3);      // bijective XCD chunking
    int nb = orig & 3, mb = orig >> 2;
    int m0 = mb * 128, cb = nb * 128;
    int lr = lane & 15, lg = lane >> 4;

    const float* a_base = v + (size_t)(m0 + wid * 32 + (lane >> 4)) * VDIM + (lane & 15) * 4;
    const unsigned short* b_base = w1T + (size_t)(cb + wid * 32 + (lane >> 3)) * W1R
                                 + (((lane & 7) ^ (lane >> 3)) * 8);

    f32x4 acc[4][4];
#pragma unroll
    for (int mt = 0; mt < 4; ++mt)
#pragma unroll
        for (int nt = 0; nt < 4; ++nt) acc[mt][nt] = (f32x4){0.f, 0.f, 0.f, 0.f};

#define MG_CVT_WRITE(DST, AR)                                                  \
    _Pragma("unroll") for (int p = 0; p < 8; ++p) {                            \
        int r = wid * 32 + (lane >> 4) + p * 4;                                \
        int boff = r * 128 + ((((lane & 15) * 8)) ^ ((r & 7) << 4));           \
        unsigned short t4[4] = {f2bf(AR[p].x), f2bf(AR[p].y),                  \
                                f2bf(AR[p].z), f2bf(AR[p].w)};                 \
        *(ushort4v*)((char*)(DST) + boff) = *(const ushort4v*)t4;              \
    }

#define MG_READ_AF()                                                           \
    _Pragma("unroll") for (int kk = 0; kk < 2; ++kk)                           \
        _Pragma("unroll") for (int mt = 0; mt < 4; ++mt) {                     \
            int R = wm * 64 + mt * 16 + lr;                                    \
            int off = R * 128 + ((kk * 64 + lg * 16) ^ ((R & 7) << 4));        \
            af[kk][mt] = *(const short8*)((const char*)&At[0] + off);          \
        }

#define MG_COMPUTE(BC)                                                         \
    _Pragma("unroll") for (int kk = 0; kk < 2; ++kk) {                         \
        short8 bf[4];                                                          \
        _Pragma("unroll") for (int nt = 0; nt < 4; ++nt) {                     \
            int R = wn * 64 + nt * 16 + lr;                                    \
            int off = R * 128 + ((kk * 64 + lg * 16) ^ ((R & 7) << 4));        \
            bf[nt] = *(const short8*)((const char*)(BC) + off);                \
        }                                                                      \
        __builtin_amdgcn_s_setprio(1);                                         \
        _Pragma("unroll") for (int mt = 0; mt < 4; ++mt)                       \
            _Pragma("unroll") for (int nt = 0; nt < 4; ++nt)                   \
                acc[mt][nt] = __builtin_amdgcn_mfma_f32_16x16x32_bf16(         \
                    af[kk][mt], bf[nt], acc[mt][nt], 0, 0, 0);                 \
        __builtin_amdgcn_s_setprio(0);                                         \
    }

    // ---- prologue: A(0) loads -> cvt -> At, B(0) DMA -> Bt[0] ----
    {
        float4 ar[8];
#pragma unroll
        for (int p = 0; p < 8; ++p) ar[p] = *(const float4*)(a_base + (size_t)p * 4 * VDIM);
#pragma unroll
        for (int o = 0; o < 4; ++o)
            gload_lds16(b_base + (size_t)o * 8 * W1R, &Bt[0][(wid * 32 + o * 8) * 64]);
        SB();
        MG_CVT_WRITE(&At[0], ar)
    }

#pragma unroll 1
    for (int t = 0; t < 15; ++t) {
        int k0 = (t + 1) * 64;
        const unsigned short* Bc = &Bt[t & 1][0];
        unsigned short* Bn = &Bt[(t + 1) & 1][0];
        // issue A(t+1)->regs and B(t+1)->LDS DMA  [12 vmem]
        float4 ar[8];
#pragma unroll
        for (int p = 0; p < 8; ++p)
            ar[p] = *(const float4*)(a_base + (size_t)p * 4 * VDIM + k0);
#pragma unroll
        for (int o = 0; o < 4; ++o)
            gload_lds16(b_base + (size_t)o * 8 * W1R + k0, &Bn[(wid * 32 + o * 8) * 64]);
        SB();
        asm volatile("s_waitcnt vmcnt(12)" ::: "memory");   // B(t) landed
        asm volatile("s_waitcnt lgkmcnt(0)" ::: "memory");  // my At writes done
        __builtin_amdgcn_s_barrier();                       // At(t)+B(t) visible
        SB();
        short8 af[2][4];
        MG_READ_AF()
        SB();
        asm volatile("s_waitcnt lgkmcnt(0)" ::: "memory");  // my af reads done
        __builtin_amdgcn_s_barrier();                       // all waves read At
        SB();
        MG_COMPUTE(Bc)
        SB();
        MG_CVT_WRITE(&At[0], ar)                            // overwrite At(t+1)
    }
    SB();
    asm volatile("s_waitcnt vmcnt(0)" ::: "memory");
    asm volatile("s_waitcnt lgkmcnt(0)" ::: "memory");
    __builtin_amdgcn_s_barrier();
    SB();
    {
        short8 af[2][4];
        MG_READ_AF()
        MG_COMPUTE(&Bt[1][0])
    }
#undef MG_COMPUTE
#undef MG_READ_AF
#undef MG_CVT_WRITE

    // ---- epilogue: relu(acc + qp) . w2 -> partial logits for cols [cb,cb+128)
    __syncthreads();
    float* qs = (float*)&At[0];         // 5 x 128 slab of qp
    float* fl = qs + 5 * 128;           // 2 x 128 reduction scratch
    int n0 = m0 / KK;
    for (int i = tid; i < 5 * 128; i += 256) {
        int nn = n0 + (i >> 7);
        if (nn >= NROWS) nn = NROWS - 1;
        qs[i] = qp[(size_t)nn * HH + cb + (i & 127)];
    }
    __syncthreads();

    float part[4][4] = {{0.f}};
#pragma unroll
    for (int nt = 0; nt < 4; ++nt) {
        int c = wn * 64 + nt * 16 + lr;
        float w2v = w2[cb + c];
#pragma unroll
        for (int mt = 0; mt < 4; ++mt)
#pragma unroll
            for (int r = 0; r < 4; ++r) {
                int row = wm * 64 + mt * 16 + lg * 4 + r;
                int ni = (m0 + row) / KK - n0;
                float pre = acc[mt][nt][r] + qs[ni * 128 + c];
                part[mt][r] += fmaxf(pre, 0.f) * w2v;
            }
    }
#pragma unroll
    for (int mt = 0; mt < 4; ++mt)
#pragma unroll
        for (int r = 0; r < 4; ++r) {
            float s = part[mt][r];
            s += __shfl_xor(s, 1, 64);
            s += __shfl_xor(s, 2, 64);
            s += __shfl_xor(s, 4, 64);
            s += __shfl_xor(s, 8, 64);
            if (lr == 0) fl[wn * 128 + wm * 64 + mt * 16 + lg * 4 + r] = s;
        }
    __syncthreads();
    if (tid < 128)
        logits4[(size_t)nb * MM + m0 + tid] = fl[tid] + fl[128 + tid];
}

// ---------------------------------------------------------------------------
// Kernel 4: masked softmax. One wave per (b,s,t); sums 4 logit partials.
// ---------------------------------------------------------------------------
__global__ __launch_bounds__(256) void softmax_kernel(const float* __restrict__ logits4,
                                                      const float* __restrict__ box_mask,
                                                      const int* __restrict__ starts,
                                                      const int* __restrict__ lengths,
                                                      float* __restrict__ out) {
    int lane = threadIdx.x & 63;
    int g = blockIdx.x * 4 + (threadIdx.x >> 6);   // 0 .. B*S*T-1
    int t   = g & (TT - 1);
    int row = g >> 4;
    int b   = row >> 2;

    int length = lengths[row];
    int start  = starts[row];

    int k = lane;
    bool kv = k < KK;
    float mval = kv ? box_mask[b * KK + k] : 0.f;
    bool act = kv && (mval != 0.f);

    float l = 0.f;
    if (act && t < length) {
        size_t idx = (size_t)(start + t) * KK + k;
        l = logits4[idx] + logits4[MM + idx] + logits4[2 * (size_t)MM + idx]
          + logits4[3 * (size_t)MM + idx];
    }

    float lm = act ? l : -1e30f;
#pragma unroll
    for (int off = 32; off >= 1; off >>= 1) lm = fmaxf(lm, __shfl_xor(lm, off, 64));

    float e = act ? expf(l - lm) : 0.f;
    float se = e;
#pragma unroll
    for (int off = 32; off >= 1; off >>= 1) se += __shfl_xor(se, off, 64);

    if (kv) out[(size_t)g * KK + k] = e / se;
}

// ---------------------------------------------------------------------------
extern "C" void kernel_launch(void* const* d_in, const int* in_sizes, int n_in,
                              void* d_out, int out_size, void* d_ws, size_t ws_size,
                              hipStream_t stream) {
    const float* v        = (const float*)d_in[0];
    const float* q        = (const float*)d_in[1];
    const float* box_mask = (const float*)d_in[2];
    const int*   tags     = (const int*)d_in[3];
    const float* w1       = (const float*)d_in[4];
    const float* b1       = (const float*)d_in[5];
    const float* w2       = (const float*)d_in[6];

    char* ws = (char*)d_ws;
    unsigned short* w1T   = (unsigned short*)ws;                 // 1,572,864 B
    float* qp      = (float*)(ws + 1572864);                     // 6,684,672 B
    float* logits4 = (float*)(ws + 1572864 + 6684672);           // 1,880,064 B
    int*   starts  = (int*)(ws + 1572864 + 6684672 + 1880064);
    int*   lengths = (int*)(ws + 1572864 + 6684672 + 1880064 + 1536);
    float* out     = (float*)d_out;

    hipLaunchKernelGGL(prep_w1T, dim3(6, 512), dim3(256), 0, stream, w1, w1T);
    hipLaunchKernelGGL(starts_kernel, dim3(1), dim3(512), 0, stream, tags, starts, lengths);
    hipLaunchKernelGGL(qproj_mfma, dim3((NROWS / 64) * 4), dim3(256), 0, stream,
                       q, w1T, b1, qp);
    hipLaunchKernelGGL(main_gemm, dim3((MM / 128) * 4), dim3(256), 0, stream,
                       v, w1T, qp, w2, logits4);
    hipLaunchKernelGGL(softmax_kernel, dim3((BB * SS * TT) / 4), dim3(256), 0, stream,
                       logits4, box_mask, starts, lengths, out);
}